// Round 15
// baseline (370.771 us; speedup 1.0000x reference)
//
#include <hip/hip_runtime.h>

// LSTMNet: SEQ=600, B=4096, IN=6, H=30, OUT=61, fp32 in/out.
// M5: one wave = 4 batch elements, fully self-contained, NO LDS in the loop.
// 1024 single-wave blocks -> 1 wave/SIMD, all 1024 SIMDs active.
//   B cols REPLICATED: col n = elem n&3 (4 copies, copy j = n>>2) -> every
//   lane's C is valid (M4 wasted 12/16 cols and needed an LDS scatter/gather
//   round-trip on the critical path; that was ~half the 1400 cy/step wall).
//   Weight rows gate-interleaved: tile-m row r = unit 4m+(r>>2), gate r&3.
//   C layout (m89-verified): col=lane&15, row=4*(l>>4)+reg -> lane (g,n):
//   C[m] f32x4 = (i,f,g,o) of unit 4m+g, elem n&3  (gates pre-grouped).
//   Nonlin ownership: lane (g,n) -> units uA=8j+g (m=2j), uB=8j+4+g (m=2j+1);
//   C[m] picked by 6 vector ternaries (cndmask tree; no runtime indexing).
//   h-return: 8 ds_bpermute on f32 hA/hB (4 distinct src addrs) + 4 cvtpk;
//   g==3 dword3 overridden to (0,1.0) bias slot (R10-verified trick).
//   Per step: 8 chained MFMA (C=Ah*Bh+xacc) + 8 off-chain x-MFMAs (x 1 iter
//   ahead, loads 2 iters ahead). Weights/xacc are MFMA operands -> AGPR-legal.

#define SEQ    600
#define BATCH  4096
#define INP    6
#define HID    30
#define NOUT   61
#define LOG2E  1.4426950408889634f
#define LOG2E2 2.8853900817779268f

typedef __fp16 f16;
typedef f16  f16x2 __attribute__((ext_vector_type(2)));
typedef f16  f16x8 __attribute__((ext_vector_type(8)));
typedef float f32x2 __attribute__((ext_vector_type(2)));
typedef float f32x4 __attribute__((ext_vector_type(4)));

__device__ __forceinline__ float rcp_(float x)  { return __builtin_amdgcn_rcpf(x); }
__device__ __forceinline__ float exp2_(float x) { return __builtin_amdgcn_exp2f(x); }
__device__ __forceinline__ unsigned cvtpk(float a, float b) {
    union { f16x2 h; unsigned u; } c;
    c.h = __builtin_amdgcn_cvt_pkrtz(a, b);
    return c.u;
}
__device__ __forceinline__ f16x8 mk8(unsigned a, unsigned b, unsigned c, unsigned d) {
    union { unsigned u[4]; f16x8 v; } x;
    x.u[0] = a; x.u[1] = b; x.u[2] = c; x.u[3] = d;
    return x.v;
}
__device__ __forceinline__ float asf(int u) {
    union { int i; float f; } c; c.i = u; return c.f;
}
__device__ __forceinline__ int asi(float f) {
    union { float f; int i; } c; c.f = f; return c.i;
}
__device__ __forceinline__ float sigm_(float x) {
    return rcp_(1.0f + exp2_(-LOG2E * x));
}
__device__ __forceinline__ float tanh_(float x) {
    return fmaf(-2.0f, rcp_(exp2_(LOG2E2 * x) + 1.0f), 1.0f);
}

extern "C" __global__ void __launch_bounds__(64, 1)
lstm_m5(const float* __restrict__ X,   const float* __restrict__ Wih,
        const float* __restrict__ Whh, const float* __restrict__ bih,
        const float* __restrict__ bhh, const float* __restrict__ W1,
        const float* __restrict__ b1,  const float* __restrict__ W2,
        const float* __restrict__ b2,  float* __restrict__ out)
{
    __shared__ float h32[4][32];   // final h per elem (epilogue only)
    __shared__ float o1s[4][32];   // fc1 activations

    const int l  = threadIdx.x;     // 0..63
    const int g  = l >> 4;          // k-group (A/B row-group)
    const int n  = l & 15;          // col
    const int e  = n & 3;           // this lane's elem slot
    const int j  = n >> 2;          // copy index -> unit-block
    const int e0 = blockIdx.x * 4;  // first elem of this wave
    const bool jb0 = (j & 1) != 0;
    const bool jb1 = (j & 2) != 0;
    const bool isg3 = (g == 3);

    // ---- pack A fragments (gate-interleaved rows; R10-verified frag map) ----
    // Lane supplies A row n of tile m: unit 4m+(n>>2), gate n&3; k = 8g+2jp(+1).
    f16x8 Ah[8], Ax[8];
    {
        const int q = n & 3;               // gate of this lane's rows
        #pragma unroll
        for (int m = 0; m < 8; ++m) {
            const int u  = 4 * m + (n >> 2);
            const bool ov = (u < HID);
            const int row = q * HID + (ov ? u : 0);
            unsigned dh[4], dx[4];
            #pragma unroll
            for (int jp = 0; jp < 4; ++jp) {
                const int k0 = 8 * g + 2 * jp, k1 = k0 + 1;
                float v0 = (ov && k0 < HID) ? Whh[row * HID + k0] : 0.f;
                float v1 = (ov && k1 < HID) ? Whh[row * HID + k1]
                         : ((ov && k1 == 31) ? (bih[row] + bhh[row]) : 0.f);
                dh[jp] = cvtpk(v0, v1);
                float w0 = (ov && k0 < INP) ? Wih[row * INP + k0] : 0.f;
                float w1 = (ov && k1 < INP) ? Wih[row * INP + k1] : 0.f;
                dx[jp] = cvtpk(w0, w1);
            }
            Ah[m] = mk8(dh[0], dh[1], dh[2], dh[3]);
            Ax[m] = mk8(dx[0], dx[1], dx[2], dx[3]);
        }
    }

    // ---- bpermute byte addrs (4 distinct; unit U elem E lives in lane
    //      16*(U&3) + 4*(U>>3) + E, reg hA if (U>>2)&1==0 else hB) ----
    const int A0 = (4 * g + e) * 4;        // dw0/dw2 first half
    const int A1 = (16 + 4 * g + e) * 4;   // dw0/dw2 second half
    const int A2 = (32 + 4 * g + e) * 4;   // dw1/dw3 first half
    const int A3 = (48 + 4 * g + e) * 4;   // dw1/dw3 second half

    // per-lane x source: elem e (cols replicate -> same addr in 4-lane groups)
    const float* xsrc = X + (size_t)(e0 + e) * INP;

    float cA = 0.f, cB = 0.f;          // cell state, units 8j+g / 8j+4+g
    float hA = 0.f, hB = 0.f;

    f32x2 xq0, xq1, xq2;
    { const float* p = xsrc; xq0 = *(const f32x2*)p; xq1 = *(const f32x2*)(p+2); xq2 = *(const f32x2*)(p+4); }

    f32x4 xcA[8], xcB[8];
    const f32x4 ZZ = {0.f, 0.f, 0.f, 0.f};

    #define XACC(DST) do {                                                     \
        const unsigned c0 = cvtpk(xq0.x, xq0.y);                               \
        const unsigned c1 = cvtpk(xq1.x, xq1.y);                               \
        const unsigned c2 = cvtpk(xq2.x, xq2.y);                               \
        const f16x8 Bx = mk8(g == 0 ? c0 : 0u, g == 0 ? c1 : 0u,               \
                             g == 0 ? c2 : 0u, 0u);                            \
        _Pragma("unroll")                                                      \
        for (int m = 0; m < 8; ++m)                                            \
            DST[m] = __builtin_amdgcn_mfma_f32_16x16x32_f16(Ax[m], Bx, ZZ, 0, 0, 0); \
    } while (0)

    XACC(xcA);                                   // x-projection for t = 0
    { const float* p = xsrc + (size_t)BATCH * INP;   // x(1)
      xq0 = *(const f32x2*)p; xq1 = *(const f32x2*)(p+2); xq2 = *(const f32x2*)(p+4); }

    #define ITER(XC, XN, T) do {                                               \
        /* Bh from hA/hB via 8 bpermutes + 4 cvtpk (no LDS) */                 \
        const int r0 = __builtin_amdgcn_ds_bpermute(A0, asi(hA));              \
        const int r1 = __builtin_amdgcn_ds_bpermute(A1, asi(hA));              \
        const int r2 = __builtin_amdgcn_ds_bpermute(A2, asi(hA));              \
        const int r3 = __builtin_amdgcn_ds_bpermute(A3, asi(hA));              \
        const int r4 = __builtin_amdgcn_ds_bpermute(A0, asi(hB));              \
        const int r5 = __builtin_amdgcn_ds_bpermute(A1, asi(hB));              \
        const int r6 = __builtin_amdgcn_ds_bpermute(A2, asi(hB));              \
        const int r7 = __builtin_amdgcn_ds_bpermute(A3, asi(hB));              \
        const unsigned dw0 = cvtpk(asf(r0), asf(r1));                          \
        const unsigned dw1 = cvtpk(asf(r2), asf(r3));                          \
        const unsigned dw2 = cvtpk(asf(r4), asf(r5));                          \
        unsigned dw3 = cvtpk(asf(r6), asf(r7));                                \
        dw3 = isg3 ? 0x3C000000u : dw3;   /* k=(30,31) -> (0, 1.0) bias */     \
        const f16x8 Bh = mk8(dw0, dw1, dw2, dw3);                              \
        f32x4 C[8];                                                            \
        _Pragma("unroll")                                                      \
        for (int m = 0; m < 8; ++m)                                            \
            C[m] = __builtin_amdgcn_mfma_f32_16x16x32_f16(Ah[m], Bh, XC[m], 0, 0, 0); \
        /* off-chain: x-projection for step T+1 from x regs loaded last iter */\
        XACC(XN);                                                              \
        /* issue x loads for step T+2 */                                       \
        { int tt = (T) + 2; if (tt > SEQ - 1) tt = SEQ - 1;                    \
          const float* p = xsrc + (size_t)tt * BATCH * INP;                    \
          xq0 = *(const f32x2*)p; xq1 = *(const f32x2*)(p+2);                  \
          xq2 = *(const f32x2*)(p+4); }                                        \
        /* select this lane's two gate-quads: m = 2j (GA), 2j+1 (GB) */        \
        const f32x4 sA0 = jb0 ? C[2] : C[0];                                   \
        const f32x4 sA1 = jb0 ? C[6] : C[4];                                   \
        const f32x4 GA  = jb1 ? sA1 : sA0;                                     \
        const f32x4 sB0 = jb0 ? C[3] : C[1];                                   \
        const f32x4 sB1 = jb0 ? C[7] : C[5];                                   \
        const f32x4 GB  = jb1 ? sB1 : sB0;                                     \
        /* nonlin: GA/GB = (i,f,g,o) */                                        \
        const float siA = sigm_(GA.x), sfA = sigm_(GA.y);                      \
        const float tgA = tanh_(GA.z), soA = sigm_(GA.w);                      \
        const float siB = sigm_(GB.x), sfB = sigm_(GB.y);                      \
        const float tgB = tanh_(GB.z), soB = sigm_(GB.w);                      \
        cA = fmaf(sfA, cA, siA * tgA);                                         \
        cB = fmaf(sfB, cB, siB * tgB);                                         \
        hA = soA * tanh_(cA);                                                  \
        hB = soB * tanh_(cB);                                                  \
    } while (0)

    for (int t = 0; t < SEQ; t += 2) {
        ITER(xcA, xcB, t);
        ITER(xcB, xcA, t + 1);
    }
    #undef ITER
    #undef XACC

    // ---- epilogue: lane (g,n) holds h of elem e, units 8j+g and 8j+4+g ----
    h32[e][8 * j + g]     = hA;
    h32[e][8 * j + 4 + g] = hB;
    asm volatile("s_waitcnt lgkmcnt(0)" ::: "memory");   // single wave

    // FC1 (M4-verified): lane (g,n) -> elem g, rows n and n+16
    {
        float hr[HID];
        #pragma unroll
        for (int k = 0; k < HID; ++k) hr[k] = h32[g][k];
        float a0 = b1[n];
        const float* w1r0 = W1 + n * HID;
        #pragma unroll
        for (int k = 0; k < HID; ++k) a0 = fmaf(w1r0[k], hr[k], a0);
        o1s[g][n] = a0;
        if (n < 14) {
            float a1 = b1[n + 16];
            const float* w1r1 = W1 + (n + 16) * HID;
            #pragma unroll
            for (int k = 0; k < HID; ++k) a1 = fmaf(w1r1[k], hr[k], a1);
            o1s[g][n + 16] = a1;
        }
    }
    asm volatile("s_waitcnt lgkmcnt(0)" ::: "memory");

    // FC2: lane (g,n) -> elem g, rows n+16r (<61)
    {
        float orr[HID];
        #pragma unroll
        for (int k = 0; k < HID; ++k) orr[k] = o1s[g][k];
        #pragma unroll
        for (int r = 0; r < 4; ++r) {
            const int o = n + 16 * r;
            if (o < NOUT) {
                float a2 = b2[o];
                const float* w2r = W2 + o * HID;
                #pragma unroll
                for (int k = 0; k < HID; ++k) a2 = fmaf(w2r[k], orr[k], a2);
                out[(size_t)(e0 + g) * NOUT + o] = a2;
            }
        }
    }
}

extern "C" void kernel_launch(void* const* d_in, const int* in_sizes, int n_in,
                              void* d_out, int out_size, void* d_ws, size_t ws_size,
                              hipStream_t stream) {
    const float* X   = (const float*)d_in[0];
    const float* Wih = (const float*)d_in[1];
    const float* Whh = (const float*)d_in[2];
    const float* bih = (const float*)d_in[3];
    const float* bhh = (const float*)d_in[4];
    const float* W1  = (const float*)d_in[5];
    const float* b1  = (const float*)d_in[6];
    const float* W2  = (const float*)d_in[7];
    const float* b2  = (const float*)d_in[8];
    float* out = (float*)d_out;

    dim3 grid(BATCH / 4);   // 1024 single-wave blocks -> 1 wave per SIMD
    dim3 block(64);
    hipLaunchKernelGGL(lstm_m5, grid, block, 0, stream,
                       X, Wih, Whh, bih, bhh, W1, b1, W2, b2, out);
}

// Round 16
// 345.140 us; speedup vs baseline: 1.0743x; 1.0743x over previous
//
#include <hip/hip_runtime.h>

// LSTMNet: SEQ=600, B=4096, IN=6, H=30, OUT=61, fp32 in/out.
// M6: one wave = 2 batch elements (8-copy cols) -> 2048 waves = 2 waves/SIMD.
// First MFMA structure with >=2 independent waves per SIMD: wave A's
// bperm->MFMA->nonlin chain latency (the invariant ~1000cy/step exposed in
// M4/M5 at 1 wave/SIMD) is covered by wave B's issue.
//   B col n = elem n&1 (8 copies, j = n>>1).  A rows gate-interleaved
//   (tile m row r: unit 4m+(r>>2), gate r&3) -> lane (g,n) C[m] f32x4 =
//   (i,f,g,o) of unit 4m+g, elem n&1.  Its OWN nonlin unit is u = 4j+g,
//   i.e. quad C[j]: one 7-ternary cndmask select, NO redistribution at all.
//   h-return: 8 ds_bpermute f32 + 4 cvtpk (M5-verified style, E2 addresses);
//   g==3 dword3 -> (0,1.0) bias slot (k=31 bias col in Ah, R10-verified).
//   Per step: 8 chained MFMA (C=Ah*Bh+xacc) + 8 off-chain x-MFMAs (x regs
//   1 iter ahead, loads 2 iters ahead).  Weights/xacc AGPR-legal.

#define SEQ    600
#define BATCH  4096
#define INP    6
#define HID    30
#define NOUT   61
#define LOG2E  1.4426950408889634f
#define LOG2E2 2.8853900817779268f

typedef __fp16 f16;
typedef f16  f16x2 __attribute__((ext_vector_type(2)));
typedef f16  f16x8 __attribute__((ext_vector_type(8)));
typedef float f32x2 __attribute__((ext_vector_type(2)));
typedef float f32x4 __attribute__((ext_vector_type(4)));

__device__ __forceinline__ float rcp_(float x)  { return __builtin_amdgcn_rcpf(x); }
__device__ __forceinline__ float exp2_(float x) { return __builtin_amdgcn_exp2f(x); }
__device__ __forceinline__ unsigned cvtpk(float a, float b) {
    union { f16x2 h; unsigned u; } c;
    c.h = __builtin_amdgcn_cvt_pkrtz(a, b);
    return c.u;
}
__device__ __forceinline__ f16x8 mk8(unsigned a, unsigned b, unsigned c, unsigned d) {
    union { unsigned u[4]; f16x8 v; } x;
    x.u[0] = a; x.u[1] = b; x.u[2] = c; x.u[3] = d;
    return x.v;
}
__device__ __forceinline__ float asf(int u) {
    union { int i; float f; } c; c.i = u; return c.f;
}
__device__ __forceinline__ int asi(float f) {
    union { float f; int i; } c; c.f = f; return c.i;
}
__device__ __forceinline__ float sigm_(float x) {
    return rcp_(1.0f + exp2_(-LOG2E * x));
}
__device__ __forceinline__ float tanh_(float x) {
    return fmaf(-2.0f, rcp_(exp2_(LOG2E2 * x) + 1.0f), 1.0f);
}

extern "C" __global__ void __launch_bounds__(64, 2)
lstm_m6(const float* __restrict__ X,   const float* __restrict__ Wih,
        const float* __restrict__ Whh, const float* __restrict__ bih,
        const float* __restrict__ bhh, const float* __restrict__ W1,
        const float* __restrict__ b1,  const float* __restrict__ W2,
        const float* __restrict__ b2,  float* __restrict__ out)
{
    __shared__ float h32[2][32];   // final h per elem (epilogue only)
    __shared__ float o1s[2][32];   // fc1 activations

    const int l  = threadIdx.x;     // 0..63
    const int g  = l >> 4;          // k-group (A/B row-group)
    const int n  = l & 15;          // col
    const int e  = n & 1;           // this lane's elem slot (0/1)
    const int j  = n >> 1;          // copy index 0..7 -> this lane's tile
    const int e0 = blockIdx.x * 2;  // first elem of this wave
    const bool jb0 = (j & 1) != 0;
    const bool jb1 = (j & 2) != 0;
    const bool jb2 = (j & 4) != 0;
    const bool isg3 = (g == 3);

    // ---- pack A fragments (gate-interleaved rows; R10-verified frag map;
    //      identical to M4/M5 — A is independent of the column meaning) ----
    f16x8 Ah[8], Ax[8];
    {
        const int q = n & 3;               // gate of this lane's A rows
        #pragma unroll
        for (int m = 0; m < 8; ++m) {
            const int u  = 4 * m + (n >> 2);
            const bool ov = (u < HID);
            const int row = q * HID + (ov ? u : 0);
            unsigned dh[4], dx[4];
            #pragma unroll
            for (int jp = 0; jp < 4; ++jp) {
                const int k0 = 8 * g + 2 * jp, k1 = k0 + 1;
                float v0 = (ov && k0 < HID) ? Whh[row * HID + k0] : 0.f;
                float v1 = (ov && k1 < HID) ? Whh[row * HID + k1]
                         : ((ov && k1 == 31) ? (bih[row] + bhh[row]) : 0.f);
                dh[jp] = cvtpk(v0, v1);
                float w0 = (ov && k0 < INP) ? Wih[row * INP + k0] : 0.f;
                float w1 = (ov && k1 < INP) ? Wih[row * INP + k1] : 0.f;
                dx[jp] = cvtpk(w0, w1);
            }
            Ah[m] = mk8(dh[0], dh[1], dh[2], dh[3]);
            Ax[m] = mk8(dx[0], dx[1], dx[2], dx[3]);
        }
    }

    // ---- bpermute byte addrs: unit U elem E lives in lane 16*(U&3)+2*(U>>2)+E.
    //      Bh dword d of lane (g,n) covers units (8g+2d, 8g+2d+1), elem e. ----
    const int A0 = (4 * g + e) * 4;            // d0 first  (unit 8g)
    const int A1 = (16 + 4 * g + e) * 4;       // d0 second (unit 8g+1)
    const int A2 = (32 + 4 * g + e) * 4;       // d1 first  (unit 8g+2)
    const int A3 = (48 + 4 * g + e) * 4;       // d1 second (unit 8g+3)
    const int A4 = (4 * g + 2 + e) * 4;        // d2 first  (unit 8g+4)
    const int A5 = (16 + 4 * g + 2 + e) * 4;   // d2 second (unit 8g+5)
    const int A6 = (32 + 4 * g + 2 + e) * 4;   // d3 first  (unit 8g+6)
    const int A7 = (48 + 4 * g + 2 + e) * 4;   // d3 second (unit 8g+7)

    // per-lane x source: elem e (32 lanes share each addr -> coalesced)
    const float* xsrc = X + (size_t)(e0 + e) * INP;

    float c = 0.f, h = 0.f;            // cell/hidden of unit 4j+g, elem e

    f32x2 xq0, xq1, xq2;
    { const float* p = xsrc; xq0 = *(const f32x2*)p; xq1 = *(const f32x2*)(p+2); xq2 = *(const f32x2*)(p+4); }

    f32x4 xcA[8], xcB[8];
    const f32x4 ZZ = {0.f, 0.f, 0.f, 0.f};

    #define XACC(DST) do {                                                     \
        const unsigned c0 = cvtpk(xq0.x, xq0.y);                               \
        const unsigned c1 = cvtpk(xq1.x, xq1.y);                               \
        const unsigned c2 = cvtpk(xq2.x, xq2.y);                               \
        const f16x8 Bx = mk8(g == 0 ? c0 : 0u, g == 0 ? c1 : 0u,               \
                             g == 0 ? c2 : 0u, 0u);                            \
        _Pragma("unroll")                                                      \
        for (int m = 0; m < 8; ++m)                                            \
            DST[m] = __builtin_amdgcn_mfma_f32_16x16x32_f16(Ax[m], Bx, ZZ, 0, 0, 0); \
    } while (0)

    XACC(xcA);                                   // x-projection for t = 0
    { const float* p = xsrc + (size_t)BATCH * INP;   // x(1)
      xq0 = *(const f32x2*)p; xq1 = *(const f32x2*)(p+2); xq2 = *(const f32x2*)(p+4); }

    #define ITER(XC, XN, T) do {                                               \
        /* Bh from h via 8 bpermutes + 4 cvtpk (no LDS) */                     \
        const int r0 = __builtin_amdgcn_ds_bpermute(A0, asi(h));               \
        const int r1 = __builtin_amdgcn_ds_bpermute(A1, asi(h));               \
        const int r2 = __builtin_amdgcn_ds_bpermute(A2, asi(h));               \
        const int r3 = __builtin_amdgcn_ds_bpermute(A3, asi(h));               \
        const int r4 = __builtin_amdgcn_ds_bpermute(A4, asi(h));               \
        const int r5 = __builtin_amdgcn_ds_bpermute(A5, asi(h));               \
        const int r6 = __builtin_amdgcn_ds_bpermute(A6, asi(h));               \
        const int r7 = __builtin_amdgcn_ds_bpermute(A7, asi(h));               \
        const unsigned dw0 = cvtpk(asf(r0), asf(r1));                          \
        const unsigned dw1 = cvtpk(asf(r2), asf(r3));                          \
        const unsigned dw2 = cvtpk(asf(r4), asf(r5));                          \
        unsigned dw3 = cvtpk(asf(r6), asf(r7));                                \
        dw3 = isg3 ? 0x3C000000u : dw3;   /* k=(30,31) -> (0, 1.0) bias */     \
        const f16x8 Bh = mk8(dw0, dw1, dw2, dw3);                              \
        f32x4 C[8];                                                            \
        _Pragma("unroll")                                                      \
        for (int m = 0; m < 8; ++m)                                            \
            C[m] = __builtin_amdgcn_mfma_f32_16x16x32_f16(Ah[m], Bh, XC[m], 0, 0, 0); \
        /* off-chain: x-projection for step T+1 from x regs loaded last iter */\
        XACC(XN);                                                              \
        /* issue x loads for step T+2 */                                       \
        { int tt = (T) + 2; if (tt > SEQ - 1) tt = SEQ - 1;                    \
          const float* p = xsrc + (size_t)tt * BATCH * INP;                    \
          xq0 = *(const f32x2*)p; xq1 = *(const f32x2*)(p+2);                  \
          xq2 = *(const f32x2*)(p+4); }                                        \
        /* select this lane's own quad: G = C[j] (7 vector ternaries) */       \
        const f32x4 s0 = jb0 ? C[1] : C[0];                                    \
        const f32x4 s1 = jb0 ? C[3] : C[2];                                    \
        const f32x4 s2 = jb0 ? C[5] : C[4];                                    \
        const f32x4 s3 = jb0 ? C[7] : C[6];                                    \
        const f32x4 t0 = jb1 ? s1 : s0;                                        \
        const f32x4 t1 = jb1 ? s3 : s2;                                        \
        const f32x4 G  = jb2 ? t1 : t0;                                        \
        /* nonlin: G = (i,f,g,o) of unit 4j+g, elem e */                       \
        const float si = sigm_(G.x), sf = sigm_(G.y);                          \
        const float tg = tanh_(G.z), so = sigm_(G.w);                          \
        c = fmaf(sf, c, si * tg);                                              \
        h = so * tanh_(c);                                                     \
    } while (0)

    for (int t = 0; t < SEQ; t += 2) {
        ITER(xcA, xcB, t);
        ITER(xcB, xcA, t + 1);
    }
    #undef ITER
    #undef XACC

    // ---- epilogue: lane (g,n) holds h of elem e, unit 4j+g ----
    h32[e][4 * j + g] = h;
    asm volatile("s_waitcnt lgkmcnt(0)" ::: "memory");   // single wave

    // FC1 (R9/R13-verified pattern): half = elem, u = lane&31
    {
        const int half = l >> 5;
        const int u    = l & 31;
        if (u < HID) {
            float a1 = b1[u];
            const float* w1r = W1 + u * HID;
            #pragma unroll
            for (int k = 0; k < HID; ++k) a1 = fmaf(w1r[k], h32[half][k], a1);
            o1s[half][u] = a1;
        }
    }
    asm volatile("s_waitcnt lgkmcnt(0)" ::: "memory");

    // FC2: out[e0+half][o] for o = u, u+30 (u=0 also 60)
    {
        const int half = l >> 5;
        const int u    = l & 31;
        if (u < HID) {
            for (int o = u; o < NOUT; o += HID) {
                float a2 = b2[o];
                const float* w2r = W2 + o * HID;
                #pragma unroll
                for (int k = 0; k < HID; ++k) a2 = fmaf(w2r[k], o1s[half][k], a2);
                out[(size_t)(e0 + half) * NOUT + o] = a2;
            }
        }
    }
}

extern "C" void kernel_launch(void* const* d_in, const int* in_sizes, int n_in,
                              void* d_out, int out_size, void* d_ws, size_t ws_size,
                              hipStream_t stream) {
    const float* X   = (const float*)d_in[0];
    const float* Wih = (const float*)d_in[1];
    const float* Whh = (const float*)d_in[2];
    const float* bih = (const float*)d_in[3];
    const float* bhh = (const float*)d_in[4];
    const float* W1  = (const float*)d_in[5];
    const float* b1  = (const float*)d_in[6];
    const float* W2  = (const float*)d_in[7];
    const float* b2  = (const float*)d_in[8];
    float* out = (float*)d_out;

    dim3 grid(BATCH / 2);   // 2048 single-wave blocks -> 2 waves per SIMD
    dim3 block(64);
    hipLaunchKernelGGL(lstm_m6, grid, block, 0, stream,
                       X, Wih, Whh, bih, bhh, W1, b1, W2, b2, out);
}

// Round 17
// 327.089 us; speedup vs baseline: 1.1335x; 1.0552x over previous
//
#include <hip/hip_runtime.h>

// LSTMNet: SEQ=600, B=4096, IN=6, H=30, OUT=61, fp32 in/out.
// M7 = M6 minus the x-MFMAs: one wave = 2 elems (8-copy cols), 2048 waves
// = 2 waves/SIMD.  M6 measured VALU(54%)+MFMA(37%) ~= 91% of wall -> issue-
// bound on inflated work.  The 8 x-projection MFMAs (half the matrix-pipe
// load, 620->310 cy/CU-step) are replaced by 12 off-chain v_dot2_f32_f16:
// each lane computes Wih.x for its OWN unit (24 MACs) and adds it after the
// quad select.  xw = 12 loop-invariant f16x2 (pinned; worst-case AGPR split
// = 24 cy/step, budgeted).
//   B col n = elem n&1 (8 copies, j = n>>1).  A rows gate-interleaved ->
//   lane (g,n): C[m] f32x4 = (i,f,g,o) of unit 4m+g, elem n&1; own unit =
//   4j+g = quad C[j] via 7-ternary cndmask tree (M6-verified).
//   h-return: 8 ds_bpermute f32 + 4 cvtpk; g==3 dword3 -> (0,1.0) bias slot
//   (bias lives in Ah col k=31; R10-verified).

#define SEQ    600
#define BATCH  4096
#define INP    6
#define HID    30
#define NOUT   61
#define LOG2E  1.4426950408889634f
#define LOG2E2 2.8853900817779268f

typedef __fp16 f16;
typedef f16  f16x2 __attribute__((ext_vector_type(2)));
typedef f16  f16x8 __attribute__((ext_vector_type(8)));
typedef float f32x2 __attribute__((ext_vector_type(2)));
typedef float f32x4 __attribute__((ext_vector_type(4)));

__device__ __forceinline__ float rcp_(float x)  { return __builtin_amdgcn_rcpf(x); }
__device__ __forceinline__ float exp2_(float x) { return __builtin_amdgcn_exp2f(x); }
__device__ __forceinline__ unsigned cvtpk(float a, float b) {
    union { f16x2 h; unsigned u; } c;
    c.h = __builtin_amdgcn_cvt_pkrtz(a, b);
    return c.u;
}
__device__ __forceinline__ f16x8 mk8(unsigned a, unsigned b, unsigned c, unsigned d) {
    union { unsigned u[4]; f16x8 v; } x;
    x.u[0] = a; x.u[1] = b; x.u[2] = c; x.u[3] = d;
    return x.v;
}
__device__ __forceinline__ float asf(int u) {
    union { int i; float f; } c; c.i = u; return c.f;
}
__device__ __forceinline__ int asi(float f) {
    union { float f; int i; } c; c.f = f; return c.i;
}
__device__ __forceinline__ float sigm_(float x) {
    return rcp_(1.0f + exp2_(-LOG2E * x));
}
__device__ __forceinline__ float tanh_(float x) {
    return fmaf(-2.0f, rcp_(exp2_(LOG2E2 * x) + 1.0f), 1.0f);
}

extern "C" __global__ void __launch_bounds__(64, 2)
lstm_m7(const float* __restrict__ X,   const float* __restrict__ Wih,
        const float* __restrict__ Whh, const float* __restrict__ bih,
        const float* __restrict__ bhh, const float* __restrict__ W1,
        const float* __restrict__ b1,  const float* __restrict__ W2,
        const float* __restrict__ b2,  float* __restrict__ out)
{
    __shared__ float h32[2][32];   // final h per elem (epilogue only)
    __shared__ float o1s[2][32];   // fc1 activations

    const int l  = threadIdx.x;     // 0..63
    const int g  = l >> 4;          // k-group (A/B row-group)
    const int n  = l & 15;          // col
    const int e  = n & 1;           // this lane's elem slot (0/1)
    const int j  = n >> 1;          // copy index 0..7 -> this lane's tile
    const int e0 = blockIdx.x * 2;  // first elem of this wave
    const bool jb0 = (j & 1) != 0;
    const bool jb1 = (j & 2) != 0;
    const bool jb2 = (j & 4) != 0;
    const bool isg3 = (g == 3);

    // ---- pack Ah fragments (gate-interleaved rows; M6-verified) ----
    f16x8 Ah[8];
    {
        const int q = n & 3;               // gate of this lane's A rows
        #pragma unroll
        for (int m = 0; m < 8; ++m) {
            const int u  = 4 * m + (n >> 2);
            const bool ov = (u < HID);
            const int row = q * HID + (ov ? u : 0);
            unsigned dh[4];
            #pragma unroll
            for (int jp = 0; jp < 4; ++jp) {
                const int k0 = 8 * g + 2 * jp, k1 = k0 + 1;
                float v0 = (ov && k0 < HID) ? Whh[row * HID + k0] : 0.f;
                float v1 = (ov && k1 < HID) ? Whh[row * HID + k1]
                         : ((ov && k1 == 31) ? (bih[row] + bhh[row]) : 0.f);
                dh[jp] = cvtpk(v0, v1);
            }
            Ah[m] = mk8(dh[0], dh[1], dh[2], dh[3]);
        }
    }

    // ---- xw: own unit's Wih rows (4 gates x 3 f16x2) ----
    const int u0 = 4 * j + g;
    const int uc = (u0 < HID) ? u0 : (HID - 1);   // pad lanes: garbage xp, never read
    f16x2 xw[12];
    #pragma unroll
    for (int q2 = 0; q2 < 4; ++q2) {
        const float* s = Wih + (q2 * HID + uc) * INP;
        xw[q2 * 3 + 0] = __builtin_amdgcn_cvt_pkrtz(s[0], s[1]);
        xw[q2 * 3 + 1] = __builtin_amdgcn_cvt_pkrtz(s[2], s[3]);
        xw[q2 * 3 + 2] = __builtin_amdgcn_cvt_pkrtz(s[4], s[5]);
    }
    #pragma unroll
    for (int k = 0; k < 12; ++k) asm("" : "+v"(xw[k]));   // block remat

    // ---- bpermute byte addrs (M6-verified): unit U elem E in lane
    //      16*(U&3)+2*(U>>2)+E;  dword d covers units (8g+2d, 8g+2d+1) ----
    const int A0 = (4 * g + e) * 4;
    const int A1 = (16 + 4 * g + e) * 4;
    const int A2 = (32 + 4 * g + e) * 4;
    const int A3 = (48 + 4 * g + e) * 4;
    const int A4 = (4 * g + 2 + e) * 4;
    const int A5 = (16 + 4 * g + 2 + e) * 4;
    const int A6 = (32 + 4 * g + 2 + e) * 4;
    const int A7 = (48 + 4 * g + 2 + e) * 4;

    const float* xsrc = X + (size_t)(e0 + e) * INP;

    float c = 0.f, h = 0.f;            // cell/hidden of unit 4j+g, elem e

    f32x2 xq0, xq1, xq2;               // x(t)
    { const float* p = xsrc; xq0 = *(const f32x2*)p; xq1 = *(const f32x2*)(p+2); xq2 = *(const f32x2*)(p+4); }

    const f32x4 ZZ = {0.f, 0.f, 0.f, 0.f};

    for (int t = 0; t < SEQ; ++t) {
        // issue x(t+1) loads (consumed next iter -> one full step of latency)
        int tt = t + 1; if (tt > SEQ - 1) tt = SEQ - 1;
        const float* p = xsrc + (size_t)tt * BATCH * INP;
        const f32x2 yq0 = *(const f32x2*)p;
        const f32x2 yq1 = *(const f32x2*)(p + 2);
        const f32x2 yq2 = *(const f32x2*)(p + 4);

        // off-chain: own-unit x-projection (12 dot2), x(t) already in regs
        const f16x2 xh0 = __builtin_amdgcn_cvt_pkrtz(xq0.x, xq0.y);
        const f16x2 xh1 = __builtin_amdgcn_cvt_pkrtz(xq1.x, xq1.y);
        const f16x2 xh2 = __builtin_amdgcn_cvt_pkrtz(xq2.x, xq2.y);
        float xpi = __builtin_amdgcn_fdot2(xw[0],  xh0, 0.f, false);
        float xpf = __builtin_amdgcn_fdot2(xw[3],  xh0, 0.f, false);
        float xpg = __builtin_amdgcn_fdot2(xw[6],  xh0, 0.f, false);
        float xpo = __builtin_amdgcn_fdot2(xw[9],  xh0, 0.f, false);
        xpi = __builtin_amdgcn_fdot2(xw[1],  xh1, xpi, false);
        xpf = __builtin_amdgcn_fdot2(xw[4],  xh1, xpf, false);
        xpg = __builtin_amdgcn_fdot2(xw[7],  xh1, xpg, false);
        xpo = __builtin_amdgcn_fdot2(xw[10], xh1, xpo, false);
        xpi = __builtin_amdgcn_fdot2(xw[2],  xh2, xpi, false);
        xpf = __builtin_amdgcn_fdot2(xw[5],  xh2, xpf, false);
        xpg = __builtin_amdgcn_fdot2(xw[8],  xh2, xpg, false);
        xpo = __builtin_amdgcn_fdot2(xw[11], xh2, xpo, false);

        // Bh from h via 8 bpermutes + 4 cvtpk (M6-verified wiring)
        const int r0 = __builtin_amdgcn_ds_bpermute(A0, asi(h));
        const int r1 = __builtin_amdgcn_ds_bpermute(A1, asi(h));
        const int r2 = __builtin_amdgcn_ds_bpermute(A2, asi(h));
        const int r3 = __builtin_amdgcn_ds_bpermute(A3, asi(h));
        const int r4 = __builtin_amdgcn_ds_bpermute(A4, asi(h));
        const int r5 = __builtin_amdgcn_ds_bpermute(A5, asi(h));
        const int r6 = __builtin_amdgcn_ds_bpermute(A6, asi(h));
        const int r7 = __builtin_amdgcn_ds_bpermute(A7, asi(h));
        const unsigned dw0 = cvtpk(asf(r0), asf(r1));
        const unsigned dw1 = cvtpk(asf(r2), asf(r3));
        const unsigned dw2 = cvtpk(asf(r4), asf(r5));
        unsigned dw3 = cvtpk(asf(r6), asf(r7));
        dw3 = isg3 ? 0x3C000000u : dw3;   // k=(30,31) -> (0, 1.0) bias slot
        const f16x8 Bh = mk8(dw0, dw1, dw2, dw3);

        // 8 h-MFMAs (C-in = 0; bias via Ah k=31)
        f32x4 C[8];
        #pragma unroll
        for (int m = 0; m < 8; ++m)
            C[m] = __builtin_amdgcn_mfma_f32_16x16x32_f16(Ah[m], Bh, ZZ, 0, 0, 0);

        // own-quad select (7 vector ternaries, M6-verified)
        const f32x4 s0 = jb0 ? C[1] : C[0];
        const f32x4 s1 = jb0 ? C[3] : C[2];
        const f32x4 s2 = jb0 ? C[5] : C[4];
        const f32x4 s3 = jb0 ? C[7] : C[6];
        const f32x4 t0 = jb1 ? s1 : s0;
        const f32x4 t1 = jb1 ? s3 : s2;
        const f32x4 G  = jb2 ? t1 : t0;

        // nonlin with x-projection folded in: gates = G + xp
        const float si = sigm_(G.x + xpi), sf = sigm_(G.y + xpf);
        const float tg = tanh_(G.z + xpg), so = sigm_(G.w + xpo);
        c = fmaf(sf, c, si * tg);
        h = so * tanh_(c);

        xq0 = yq0; xq1 = yq1; xq2 = yq2;
    }

    // ---- epilogue (M6-verified) ----
    h32[e][4 * j + g] = h;
    asm volatile("s_waitcnt lgkmcnt(0)" ::: "memory");   // single wave

    {
        const int half = l >> 5;
        const int u    = l & 31;
        if (u < HID) {
            float a1 = b1[u];
            const float* w1r = W1 + u * HID;
            #pragma unroll
            for (int k = 0; k < HID; ++k) a1 = fmaf(w1r[k], h32[half][k], a1);
            o1s[half][u] = a1;
        }
    }
    asm volatile("s_waitcnt lgkmcnt(0)" ::: "memory");

    {
        const int half = l >> 5;
        const int u    = l & 31;
        if (u < HID) {
            for (int o = u; o < NOUT; o += HID) {
                float a2 = b2[o];
                const float* w2r = W2 + o * HID;
                #pragma unroll
                for (int k = 0; k < HID; ++k) a2 = fmaf(w2r[k], o1s[half][k], a2);
                out[(size_t)(e0 + half) * NOUT + o] = a2;
            }
        }
    }
}

extern "C" void kernel_launch(void* const* d_in, const int* in_sizes, int n_in,
                              void* d_out, int out_size, void* d_ws, size_t ws_size,
                              hipStream_t stream) {
    const float* X   = (const float*)d_in[0];
    const float* Wih = (const float*)d_in[1];
    const float* Whh = (const float*)d_in[2];
    const float* bih = (const float*)d_in[3];
    const float* bhh = (const float*)d_in[4];
    const float* W1  = (const float*)d_in[5];
    const float* b1  = (const float*)d_in[6];
    const float* W2  = (const float*)d_in[7];
    const float* b2  = (const float*)d_in[8];
    float* out = (float*)d_out;

    dim3 grid(BATCH / 2);   // 2048 single-wave blocks -> 2 waves per SIMD
    dim3 block(64);
    hipLaunchKernelGGL(lstm_m7, grid, block, 0, stream,
                       X, Wih, Whh, bih, bhh, W1, b1, W2, b2, out);
}